// Round 5
// baseline (221.591 us; speedup 1.0000x reference)
//
#include <hip/hip_runtime.h>
#include <hip/hip_bf16.h>

// Problem constants
#define C_   32
#define S_   20
#define V_   8000     // 20^3
#define K3_  125
#define OC_  375      // 3*K3
#define NP_  384      // padded N
#define KK_  4000     // 32*125

// Workspace layout (float offsets). Peak 2.704M floats = 10.82 MB (unchanged).
#define WS_ATTN1T 0                        // fp32 [v][c]          256000
#define WS_XT     256000                   // f16  [v][c]          128000 fl
#define WS_WDWT   384000                   // fp32 [k][c]            4000
#define WS_WSPT   388000                   // fp32 [k][c]           10976
#define WS_WPWT   398976                   // fp32 [c][o]            1024
#define WS_OFFB   400000                   // f16  [v][384]       1536000 fl
#define WS_BPREP  1936000                  // f16 [n][k] 768000 fl; dead after gemm
#define WS_XP     1936000                  //   -> reused: half2 [v][c] 256000 fl
#define WS_ATTN2T 2192000                  //   -> reused: fp32 [v][c] 256000 fl
// Zero page: first 16 floats of ATTN1T region (dead until deform_kernel).
#define WS_ZERO   WS_ATTN1T

typedef __attribute__((ext_vector_type(8))) short bf16x8;
typedef __attribute__((ext_vector_type(4))) float f32x4;
typedef __fp16 h2_t __attribute__((ext_vector_type(2)));   // matches builtins

static __device__ __forceinline__ unsigned short f2h(float f) {
    _Float16 h = (_Float16)f;
    return __builtin_bit_cast(unsigned short, h);
}
static __device__ __forceinline__ float h2f(unsigned short b) {
    return (float)__builtin_bit_cast(_Float16, b);
}
static __device__ __forceinline__ h2_t bch2(unsigned u) {
    return __builtin_bit_cast(h2_t, u);
}
static __device__ __forceinline__ unsigned pkh2(float a, float b) {
#if __has_builtin(__builtin_amdgcn_cvt_pkrtz)
    return __builtin_bit_cast(unsigned, __builtin_amdgcn_cvt_pkrtz(a, b));
#else
    return (unsigned)f2h(a) | ((unsigned)f2h(b) << 16);
#endif
}
static __device__ __forceinline__ float dot2(unsigned xu, unsigned wu, float c) {
#if __has_builtin(__builtin_amdgcn_fdot2)
    return __builtin_amdgcn_fdot2(bch2(xu), bch2(wu), c, false);
#else
    h2_t xh = bch2(xu), wh = bch2(wu);
    return c + (float)xh[0] * (float)wh[0] + (float)xh[1] * (float)wh[1];
#endif
}

// ---------------------------------------------------------------------------
// Transposes: xt[v][c] f16; wdwT[k][c]; wspT[k][c]; wpwT[c][o] (fp32).
// Also zeroes the 64B zero page used by gemm's OOB lane redirect.
// ---------------------------------------------------------------------------
__global__ __launch_bounds__(256) void transpose_kernel(
    const float* __restrict__ x,
    const float* __restrict__ w_dw,
    const float* __restrict__ w_sp,
    const float* __restrict__ w_pw,
    unsigned short* __restrict__ xt,
    float* __restrict__ wdwT,
    float* __restrict__ wspT,
    float* __restrict__ wpwT,
    float* __restrict__ zpage)
{
    int i = blockIdx.x * 256 + threadIdx.x;
    if (i < 256000) {
        int v = i >> 5, c = i & 31;
        xt[i] = f2h(x[c * V_ + v]);
        return;
    }
    int j = i - 256000;
    if (j < 4000)  { wdwT[j] = w_dw[(j & 31) * K3_ + (j >> 5)]; return; }
    j -= 4000;
    if (j < 10976) { wspT[j] = w_sp[(j & 31) * 343 + (j >> 5)]; return; }
    j -= 10976;
    if (j < 1024)  { wpwT[j] = w_pw[(j & 31) * 32 + (j >> 5)]; return; }
    j -= 1024;
    if (j < 16)    { zpage[j] = 0.f; return; }
}

// ---------------------------------------------------------------------------
// Weight transform: Bprep[n][k] f16, k = tap*32 + c; n >= 375 zeroed.
// ---------------------------------------------------------------------------
__global__ __launch_bounds__(256) void prep_b_kernel(
    const float* __restrict__ w_off, unsigned short* __restrict__ Bprep)
{
    int idx = blockIdx.x * 256 + threadIdx.x;
    if (idx >= NP_ * KK_) return;
    int n = idx / KK_, r = idx % KK_;
    int tap = r >> 5, c = r & 31;
    float v = (n < OC_) ? w_off[n * KK_ + c * K3_ + tap] : 0.f;
    Bprep[idx] = f2h(v);
}

// ---------------------------------------------------------------------------
// Offset conv as implicit-GEMM MFMA (f16): D[8000][384] = A[8000][4000]*B.
// Block tile 128x128, wave tile 64x64 (4 waves 2x2), BK=64 (2 taps/iter).
// 2-phase pipeline, global_load_lds staging (2 rows per thread per matrix
// per h), double-buffered LDS (64 KB), one barrier per K-step.
// Grid = 63x3 = 189 blocks -> single round on 256 CUs (was 750 blocks /
// 2.93 rounds at 64x64): FLOP per LDS-byte doubles AND round count drops.
// LDS XOR-swizzle (T2, both-sides): write side fetches inverse-swizzled
// global chunk (linear LDS dest, hardware-imposed); read side XORs quad
// with (lrow>>1)&3 (invariant under wr/mi row offsets, multiples of 8).
// Writes offbT[v][n] f16 (+bias).
// ---------------------------------------------------------------------------
__global__ __launch_bounds__(256) void gemm_off_kernel(
    const unsigned short* __restrict__ xt,
    const unsigned short* __restrict__ Bprep,
    const float* __restrict__ b_off,
    const float* __restrict__ zpage,
    unsigned short* __restrict__ offbT)
{
    __shared__ unsigned short A_lds[2][2][128 * 32];  // [buf][h][row*32+k] 32KB
    __shared__ unsigned short B_lds[2][2][128 * 32];  // 32KB

    const int t    = threadIdx.x;
    const int lane = t & 63;
    const int wave = t >> 6;
    const int wr   = wave >> 1;
    const int wc   = wave & 1;
    const int quad = lane >> 4;
    const int lrow = lane & 15;
    const int M0   = blockIdx.x * 128;
    const int N0   = blockIdx.y * 128;

    // Staging: thread t's phys LDS dest = t*16B (+4096B for row-half 1).
    // Inverse-swizzled logical chunk: (t&3) ^ ((t>>3)&3) — identical for
    // both row halves (64 adds a multiple of 4 to row>>1).
    const int srow = t >> 2;
    const int soff = ((t & 3) ^ ((t >> 3) & 3)) * 8;   // shorts, swizzled
    const int mg0 = M0 + srow;                          // < 8000 always
    const int mg1 = M0 + 64 + srow;                     // may exceed 7999
    const int az0 = mg0 / 400, arm0 = mg0 % 400;
    const int ay0 = arm0 / 20, ax0 = arm0 % 20;
    const int az1 = mg1 / 400, arm1 = mg1 % 400;
    const int ay1 = arm1 / 20, ax1 = arm1 % 20;
    const bool m1ok = mg1 < V_;
    const unsigned short* brow0 = Bprep + (size_t)(N0 + srow) * KK_;
    const unsigned short* brow1 = Bprep + (size_t)(N0 + 64 + srow) * KK_;
    const unsigned short* zp    = (const unsigned short*)zpage;
    // Read-side swizzle constant.
    const int xorc = (lrow >> 1) & 3;

    f32x4 acc[4][4] = {};

    auto stage = [&](int buf, int tap0) {
        #pragma unroll
        for (int h = 0; h < 2; ++h) {
            int tap = tap0 + h;
            int kz = tap / 25, ky = (tap / 5) % 5, kx = tap % 5;
            bool intap = tap < K3_;
            int zi0 = az0 - 2 + kz, yi0 = ay0 - 2 + ky, xi0 = ax0 - 2 + kx;
            bool ok0 = intap & ((unsigned)zi0 < (unsigned)S_)
                             & ((unsigned)yi0 < (unsigned)S_)
                             & ((unsigned)xi0 < (unsigned)S_);
            int zi1 = az1 - 2 + kz, yi1 = ay1 - 2 + ky, xi1 = ax1 - 2 + kx;
            bool ok1 = intap & m1ok & ((unsigned)zi1 < (unsigned)S_)
                             & ((unsigned)yi1 < (unsigned)S_)
                             & ((unsigned)xi1 < (unsigned)S_);
            const unsigned short* ga0 = ok0 ? (xt + (zi0*400 + yi0*20 + xi0)*32 + soff) : zp;
            const unsigned short* ga1 = ok1 ? (xt + (zi1*400 + yi1*20 + xi1)*32 + soff) : zp;
            const unsigned short* gb0 = intap ? (brow0 + tap*32 + soff) : zp;
            const unsigned short* gb1 = intap ? (brow1 + tap*32 + soff) : zp;
            __builtin_amdgcn_global_load_lds(
                (const __attribute__((address_space(1))) void*)ga0,
                (__attribute__((address_space(3))) void*)(&A_lds[buf][h][t * 8]),
                16, 0, 0);
            __builtin_amdgcn_global_load_lds(
                (const __attribute__((address_space(1))) void*)ga1,
                (__attribute__((address_space(3))) void*)(&A_lds[buf][h][2048 + t * 8]),
                16, 0, 0);
            __builtin_amdgcn_global_load_lds(
                (const __attribute__((address_space(1))) void*)gb0,
                (__attribute__((address_space(3))) void*)(&B_lds[buf][h][t * 8]),
                16, 0, 0);
            __builtin_amdgcn_global_load_lds(
                (const __attribute__((address_space(1))) void*)gb1,
                (__attribute__((address_space(3))) void*)(&B_lds[buf][h][2048 + t * 8]),
                16, 0, 0);
        }
    };

    stage(0, 0);
    __syncthreads();

    int cur = 0;
    for (int it = 0; it < 63; ++it) {
        if (it < 62) stage(cur ^ 1, (it + 1) * 2);
        #pragma unroll
        for (int h = 0; h < 2; ++h) {
            bf16x8 af[4], bf[4];
            #pragma unroll
            for (int mi = 0; mi < 4; ++mi)
                af[mi] = *(const bf16x8*)&A_lds[cur][h][(wr * 64 + mi * 16 + lrow) * 32 + (quad ^ xorc) * 8];
            #pragma unroll
            for (int ni = 0; ni < 4; ++ni)
                bf[ni] = *(const bf16x8*)&B_lds[cur][h][(wc * 64 + ni * 16 + lrow) * 32 + (quad ^ xorc) * 8];
            #pragma unroll
            for (int mi = 0; mi < 4; ++mi)
                #pragma unroll
                for (int ni = 0; ni < 4; ++ni)
                    acc[mi][ni] = __builtin_amdgcn_mfma_f32_16x16x32_f16(
                        af[mi], bf[ni], acc[mi][ni], 0, 0, 0);
        }
        __syncthreads();
        cur ^= 1;
    }

    #pragma unroll
    for (int mi = 0; mi < 4; ++mi) {
        #pragma unroll
        for (int ni = 0; ni < 4; ++ni) {
            int n = N0 + wc * 64 + ni * 16 + lrow;
            if (n < OC_) {
                float bias = b_off[n];
                #pragma unroll
                for (int r = 0; r < 4; ++r) {
                    int row = wr * 64 + mi * 16 + quad * 4 + r;
                    if (M0 + row < V_)
                        offbT[(size_t)(M0 + row) * 384 + n] = f2h(acc[mi][ni][r] + bias);
                }
            }
        }
    }
}

// ---------------------------------------------------------------------------
// xp[v][c] = half2(x[v][c], x[v+1][c]) — makes the (w0,w1) trilinear x-pair
// a single dword load in deform. xp[7999].y = 0 (never used with nonzero wt).
// ---------------------------------------------------------------------------
__global__ __launch_bounds__(256) void pack_xp_kernel(
    const unsigned short* __restrict__ xt, unsigned* __restrict__ xp)
{
    int i = blockIdx.x * 256 + threadIdx.x;
    if (i >= 256000) return;
    unsigned lo = xt[i];
    unsigned hi = (i < 256000 - 32) ? (unsigned)xt[i + 32] : 0u;
    xp[i] = lo | (hi << 16);
}

// ---------------------------------------------------------------------------
// Deformable depthwise sample, two-phase.
// Phase 1: per (voxel, tap) geometry -> 4 packed half2 weights (trilinear
//          factors pre-multiplied) + 4 final gather indices. 32B/entry.
// Phase 2: thread=(v,c); 2 broadcast LDS reads, 4 dword gathers, 4 fdot2.
// ---------------------------------------------------------------------------
#define VB 8
__global__ __launch_bounds__(256) void deform_kernel(
    const unsigned* __restrict__ xp,
    const float* __restrict__ wdwT,
    const float* __restrict__ b_dw,
    const unsigned short* __restrict__ offbT,
    float* __restrict__ attn1T)
{
    __shared__ unsigned sw[VB * 128 * 8];   // 32 KB, 32B per (v,tap) entry
    const int tid = threadIdx.x;
    const int Vb = blockIdx.x * VB;

    for (int idx = tid; idx < VB * 128; idx += 256) {
        int vl = idx >> 7, tap = idx & 127;
        if (tap < K3_) {
            int v = Vb + vl;
            int z = v / 400, rm = v % 400;
            int y = rm / 20, xx = rm % 20;
            int kz = tap / 25, ky = (tap / 5) % 5, kx = tap % 5;
            const unsigned short* ob = offbT + v * 384 + 3 * tap;
            float pd = (float)(z - 2 + kz) + h2f(ob[0]);
            float ph = (float)(y - 2 + ky) + h2f(ob[1]);
            float pw = (float)(xx - 2 + kx) + h2f(ob[2]);
            float fd0 = floorf(pd), fh0 = floorf(ph), fw0 = floorf(pw);
            float fd = pd - fd0, fh = ph - fh0, fw = pw - fw0;
            int id = (int)fd0, ih = (int)fh0, iw = (int)fw0;
            int d0 = min(max(id, 0), S_ - 1), d1 = min(max(id + 1, 0), S_ - 1);
            int h0 = min(max(ih, 0), S_ - 1), h1 = min(max(ih + 1, 0), S_ - 1);
            float wd0 = ((unsigned)id       < (unsigned)S_) ? 1.f - fd : 0.f;
            float wd1 = ((unsigned)(id + 1) < (unsigned)S_) ? fd       : 0.f;
            float wh0 = ((unsigned)ih       < (unsigned)S_) ? 1.f - fh : 0.f;
            float wh1 = ((unsigned)(ih + 1) < (unsigned)S_) ? fh       : 0.f;
            float ww0 = ((unsigned)iw       < (unsigned)S_) ? 1.f - fw : 0.f;
            float ww1 = ((unsigned)(iw + 1) < (unsigned)S_) ? fw       : 0.f;
            // x-pair via xp[p] = (x[p], x[p+1]); iw<0 handled by weight swap.
            int px; float wwa, wwb;
            if (iw < 0) { px = 0;             wwa = ww1; wwb = 0.f; }
            else        { px = min(iw, S_-1); wwa = ww0; wwb = ww1; }
            int r00 = d0 * 400 + h0 * 20 + px;
            int r01 = d0 * 400 + h1 * 20 + px;
            int r10 = d1 * 400 + h0 * 20 + px;
            int r11 = d1 * 400 + h1 * 20 + px;
            float w00 = wd0 * wh0, w01 = wd0 * wh1;
            float w10 = wd1 * wh0, w11 = wd1 * wh1;
            unsigned* q = &sw[idx * 8];
            q[0] = pkh2(w00 * wwa, w00 * wwb);
            q[1] = pkh2(w01 * wwa, w01 * wwb);
            q[2] = pkh2(w10 * wwa, w10 * wwb);
            q[3] = pkh2(w11 * wwa, w11 * wwb);
            q[4] = (unsigned)r00 | ((unsigned)r01 << 16);
            q[5] = (unsigned)r10 | ((unsigned)r11 << 16);
        }
    }
    __syncthreads();

    const int c = tid & 31;
    const int vl = tid >> 5;
    const int v = Vb + vl;
    const unsigned* xpc = xp + c;
    float acc = 0.f;
    #pragma unroll 4
    for (int tap = 0; tap < K3_; ++tap) {
        const unsigned* q = &sw[(vl * 128 + tap) * 8];
        unsigned w00u = q[0], w01u = q[1], w10u = q[2], w11u = q[3];
        unsigned pA = q[4], pB = q[5];
        int p00 = pA & 0xFFFFu, p01 = pA >> 16;
        int p10 = pB & 0xFFFFu, p11 = pB >> 16;
        float s = dot2(xpc[p00 * 32], w00u,
                  dot2(xpc[p01 * 32], w01u,
                  dot2(xpc[p10 * 32], w10u,
                  dot2(xpc[p11 * 32], w11u, 0.f))));
        acc += wdwT[tap * 32 + c] * s;
    }
    attn1T[v * 32 + c] = acc + b_dw[c];
}

// ---------------------------------------------------------------------------
// Depthwise 7^3 conv, dilation 3, pad 9, channel-last, coalesced.
// ---------------------------------------------------------------------------
__global__ __launch_bounds__(256) void spatial_kernel(
    const float* __restrict__ wspT,
    const float* __restrict__ b_sp,
    const float* __restrict__ attn1T,
    float* __restrict__ attn2T)
{
    int t = threadIdx.x;
    int c = t & 31;
    int v = blockIdx.x * 8 + (t >> 5);
    int z = v / 400, rm = v % 400;
    int y = rm / 20, xx = rm % 20;

    float acc = 0.f;
    #pragma unroll 1
    for (int kz = 0; kz < 7; ++kz) {
        int zi = z - 9 + 3 * kz;
        bool zv = (unsigned)zi < (unsigned)S_;
        int zc2 = min(max(zi, 0), S_ - 1);
        #pragma unroll 1
        for (int ky = 0; ky < 7; ++ky) {
            int yi = y - 9 + 3 * ky;
            bool yv = (unsigned)yi < (unsigned)S_;
            int yc2 = min(max(yi, 0), S_ - 1);
            int abase = (zc2 * 400 + yc2 * 20) * 32 + c;
            int wbase = (kz * 49 + ky * 7) * 32 + c;
            #pragma unroll
            for (int kx = 0; kx < 7; ++kx) {
                int xi = xx - 9 + 3 * kx;
                bool xv = (unsigned)xi < (unsigned)S_;
                int xc2 = min(max(xi, 0), S_ - 1);
                float a = attn1T[abase + xc2 * 32];
                float w = wspT[wbase + kx * 32];
                acc += (zv && yv && xv) ? a * w : 0.f;
            }
        }
    }
    attn2T[v * 32 + c] = acc + b_sp[c];
}

// ---------------------------------------------------------------------------
// Pointwise 32x32 + bias, gate: out[o][v] = x[o][v] * attn.
// ---------------------------------------------------------------------------
__global__ __launch_bounds__(256) void pw_kernel(
    const float* __restrict__ x,
    const float* __restrict__ wpwT,
    const float* __restrict__ b_pw,
    const float* __restrict__ attn2T,
    float* __restrict__ out)
{
    int t = threadIdx.x;
    int o = t & 31;
    int v = blockIdx.x * 8 + (t >> 5);
    float acc = b_pw[o];
    #pragma unroll
    for (int c = 0; c < C_; ++c)
        acc += wpwT[c * 32 + o] * attn2T[v * 32 + c];
    out[o * V_ + v] = x[o * V_ + v] * acc;
}

// ---------------------------------------------------------------------------
extern "C" void kernel_launch(void* const* d_in, const int* in_sizes, int n_in,
                              void* d_out, int out_size, void* d_ws, size_t ws_size,
                              hipStream_t stream)
{
    const float* x     = (const float*)d_in[0];
    const float* w_off = (const float*)d_in[1];
    const float* b_off = (const float*)d_in[2];
    const float* w_dw  = (const float*)d_in[3];
    const float* b_dw  = (const float*)d_in[4];
    const float* w_sp  = (const float*)d_in[5];
    const float* b_sp  = (const float*)d_in[6];
    const float* w_pw  = (const float*)d_in[7];
    const float* b_pw  = (const float*)d_in[8];
    float* ws = (float*)d_ws;
    float* out = (float*)d_out;

    unsigned short* xt    = (unsigned short*)(ws + WS_XT);
    unsigned short* offbT = (unsigned short*)(ws + WS_OFFB);
    unsigned short* Bprep = (unsigned short*)(ws + WS_BPREP);
    unsigned*       xp    = (unsigned*)(ws + WS_XP);

    hipLaunchKernelGGL(transpose_kernel, dim3((272016 + 255) / 256), dim3(256), 0, stream,
                       x, w_dw, w_sp, w_pw, xt,
                       ws + WS_WDWT, ws + WS_WSPT, ws + WS_WPWT, ws + WS_ZERO);

    hipLaunchKernelGGL(prep_b_kernel, dim3((NP_ * KK_ + 255) / 256), dim3(256), 0, stream,
                       w_off, Bprep);

    hipLaunchKernelGGL(gemm_off_kernel, dim3(63, 3), dim3(256), 0, stream,
                       xt, Bprep, b_off, ws + WS_ZERO, offbT);

    hipLaunchKernelGGL(pack_xp_kernel, dim3(1000), dim3(256), 0, stream,
                       xt, xp);

    hipLaunchKernelGGL(deform_kernel, dim3(1000), dim3(256), 0, stream,
                       xp, ws + WS_WDWT, b_dw, offbT, ws + WS_ATTN1T);

    hipLaunchKernelGGL(spatial_kernel, dim3(1000), dim3(256), 0, stream,
                       ws + WS_WSPT, b_sp, ws + WS_ATTN1T, ws + WS_ATTN2T);

    hipLaunchKernelGGL(pw_kernel, dim3(1000), dim3(256), 0, stream,
                       x, ws + WS_WPWT, b_pw, ws + WS_ATTN2T, out);
}